// Round 1
// baseline (7240.803 us; speedup 1.0000x reference)
//
#include <hip/hip_runtime.h>
#include <math.h>

#define NN 4096
#define FF 128
#define CD 100
#define OT_ITERS 20

// ---------- wave reduce helpers (wave = 64 on CDNA) ----------
__device__ __forceinline__ float waveSum(float v){
#pragma unroll
  for (int o=32;o>0;o>>=1) v += __shfl_down(v,o);
  return v;
}
__device__ __forceinline__ float waveMax(float v){
#pragma unroll
  for (int o=32;o>0;o>>=1) v = fmaxf(v,__shfl_down(v,o));
  return v;
}
__device__ __forceinline__ float waveMin(float v){
#pragma unroll
  for (int o=32;o>0;o>>=1) v = fminf(v,__shfl_down(v,o));
  return v;
}

// ---------- embed GEMM: out[4096x128] = A[4096xK] @ W[Kx128] + b ----------
__global__ __launch_bounds__(256) void embed_gemm(const float* __restrict__ A,
                                                  const float* __restrict__ W,
                                                  const float* __restrict__ bias,
                                                  float* __restrict__ out, int K)
{
  __shared__ float As[16][64];
  __shared__ float Ws[64][128];
  const int tid = threadIdx.x;
  const int tx = tid & 127, ty = tid >> 7;
  const int row0 = blockIdx.x * 16;
  float acc[8];
#pragma unroll
  for (int r=0;r<8;++r) acc[r]=0.f;
  for (int k0 = 0; k0 < K; k0 += 64) {
    {
      int r = tid >> 4, c4 = tid & 15;
      *(float4*)&As[r][c4*4] = *(const float4*)&A[(size_t)(row0+r)*K + k0 + c4*4];
    }
#pragma unroll
    for (int it=0; it<8; ++it) {
      int f4 = tid + it*256;
      int kk = f4 >> 5, c4 = f4 & 31;
      *(float4*)&Ws[kk][c4*4] = *(const float4*)&W[(size_t)(k0+kk)*FF + c4*4];
    }
    __syncthreads();
    for (int kk=0; kk<64; kk+=4) {
      float a[8][4];
#pragma unroll
      for (int rr=0;rr<8;++rr) *(float4*)a[rr] = *(const float4*)&As[ty*8+rr][kk];
#pragma unroll
      for (int q=0;q<4;++q) {
        float b = Ws[kk+q][tx];
#pragma unroll
        for (int rr=0;rr<8;++rr) acc[rr] += a[rr][q]*b;
      }
    }
    __syncthreads();
  }
#pragma unroll
  for (int rr=0;rr<8;++rr)
    out[(size_t)(row0+ty*8+rr)*FF + tx] = acc[rr] + bias[tx];
}

// ---------- row l2 normalize (d=128), block=128 ----------
__global__ __launch_bounds__(128) void l2norm_rows(float* __restrict__ f)
{
  __shared__ float sred[2];
  int i = blockIdx.x, t = threadIdx.x;
  float v = f[(size_t)i*FF + t];
  float s = waveSum(v*v);
  int lane = t & 63, wid = t >> 6;
  if (lane==0) sred[wid]=s;
  __syncthreads();
  float tot = sred[0]+sred[1];
  f[(size_t)i*FF + t] = v / sqrtf(tot);
}

// ---------- softmax rows of l[4096x100] -> S, and w = ||S_row||_2 ----------
__global__ __launch_bounds__(128) void softmax_rows(const float* __restrict__ l,
                                                    float* __restrict__ S,
                                                    float* __restrict__ w)
{
  __shared__ float sm[2], ss[2], sq[2];
  int i = blockIdx.x, t = threadIdx.x;
  int lane = t & 63, wid = t >> 6;
  float x = (t < CD) ? l[(size_t)i*CD + t] : -3.4e38f;
  float m = waveMax(x);
  if (lane==0) sm[wid]=m;
  __syncthreads();
  m = fmaxf(sm[0], sm[1]);
  float e = (t < CD) ? __expf(x - m) : 0.f;
  float s = waveSum(e);
  if (lane==0) ss[wid]=s;
  __syncthreads();
  float tot = ss[0]+ss[1];
  float sv = e / tot;
  if (t < CD) S[(size_t)i*CD + t] = sv;
  float q = waveSum(sv*sv);
  if (lane==0) sq[wid]=q;
  __syncthreads();
  if (t==0) w[i] = sqrtf(sq[0]+sq[1]);
}

// ---------- knn: idx[i][0]=i plus top-7 cosine neighbors ----------
__global__ __launch_bounds__(256) void knn_topk(const float* __restrict__ S,
                                                const float* __restrict__ w,
                                                int* __restrict__ idx)
{
  __shared__ float si[128];
  __shared__ float redv[256];
  __shared__ int   redi[256];
  int i = blockIdx.x, tid = threadIdx.x;
  if (tid < 128) si[tid] = (tid < CD) ? S[(size_t)i*CD + tid] : 0.f;
  __syncthreads();
  float wi = w[i];
  float bv[7]; int bi[7];
#pragma unroll
  for (int m=0;m<7;++m){ bv[m]=-3.4e38f; bi[m]=-1; }
  const float4* si4 = (const float4*)si;
  for (int j = tid; j < NN; j += 256) {
    if (j == i) continue;
    const float4* sj4 = (const float4*)&S[(size_t)j*CD];
    float dot = 0.f;
#pragma unroll
    for (int k=0;k<25;++k) {
      float4 a = si4[k], b = sj4[k];
      dot += a.x*b.x + a.y*b.y + a.z*b.z + a.w*b.w;
    }
    float cv = dot / fmaxf(wi * w[j], 1e-7f);
    if (cv > bv[6]) {
      int m = 6;
      while (m > 0 && cv > bv[m-1]) { bv[m]=bv[m-1]; bi[m]=bi[m-1]; --m; }
      bv[m]=cv; bi[m]=j;
    }
  }
  if (tid==0) idx[(size_t)i*8] = i;
  for (int m=0;m<7;++m) {
    redv[tid]=bv[0]; redi[tid]=tid;
    __syncthreads();
    for (int s=128;s>=1;s>>=1) {
      if (tid < s) {
        if (redv[tid+s] > redv[tid]) { redv[tid]=redv[tid+s]; redi[tid]=redi[tid+s]; }
      }
      __syncthreads();
    }
    int wt = redi[0];
    if (tid == wt) {
      idx[(size_t)i*8 + 1 + m] = bi[0];
#pragma unroll
      for (int q=0;q<6;++q){ bv[q]=bv[q+1]; bi[q]=bi[q+1]; }
      bv[6]=-3.4e38f; bi[6]=-1;
    }
    __syncthreads();
  }
}

// ---------- encoder: out = l2norm(concat(h, mean(h[idx])) @ W + b) ----------
__global__ __launch_bounds__(128) void encoder_kernel(const float* __restrict__ h,
                                                      const int* __restrict__ idx,
                                                      const float* __restrict__ W,
                                                      const float* __restrict__ bias,
                                                      float* __restrict__ out)
{
  __shared__ float hin[256];
  __shared__ float sred[2];
  int i = blockIdx.x, t = threadIdx.x;
  float hv = h[(size_t)i*FF + t];
  float agg = 0.f;
#pragma unroll
  for (int m=0;m<8;++m) agg += h[(size_t)idx[i*8+m]*FF + t];
  agg *= 0.125f;
  hin[t] = hv; hin[FF + t] = agg;
  __syncthreads();
  float acc = bias[t];
  for (int k=0;k<256;++k) acc += hin[k] * W[(size_t)k*FF + t];
  float s = waveSum(acc*acc);
  int lane = t & 63, wid = t >> 6;
  if (lane==0) sred[wid]=s;
  __syncthreads();
  float tot = sred[0]+sred[1];
  out[(size_t)i*FF + t] = acc / sqrtf(tot);
}

// ---------- C[4096x4096] = A[4096x128] @ B[4096x128]^T ----------
__global__ __launch_bounds__(256) void gemm_bt(const float* __restrict__ A,
                                               const float* __restrict__ B,
                                               float* __restrict__ C)
{
  __shared__ float As[64][68];   // row-major [row][k]
  __shared__ float Bs[64][68];   // transposed [k][col]
  const int tid = threadIdx.x;
  const int tc = tid & 15, tr = tid >> 4;
  const int i0 = blockIdx.y * 64, j0 = blockIdx.x * 64;
  float acc[4][4];
#pragma unroll
  for (int a=0;a<4;++a)
#pragma unroll
    for (int b=0;b<4;++b) acc[a][b]=0.f;
  for (int k0 = 0; k0 < FF; k0 += 64) {
#pragma unroll
    for (int it=0; it<4; ++it) {
      int f4 = tid + it*256;
      int r = f4 >> 4, c4 = f4 & 15;
      *(float4*)&As[r][c4*4] = *(const float4*)&A[(size_t)(i0+r)*FF + k0 + c4*4];
      float4 bvv = *(const float4*)&B[(size_t)(j0+r)*FF + k0 + c4*4];
      Bs[c4*4+0][r] = bvv.x; Bs[c4*4+1][r] = bvv.y;
      Bs[c4*4+2][r] = bvv.z; Bs[c4*4+3][r] = bvv.w;
    }
    __syncthreads();
    for (int kk=0; kk<64; kk+=4) {
      float a[4][4];
#pragma unroll
      for (int q=0;q<4;++q) *(float4*)a[q] = *(const float4*)&As[tr*4+q][kk];
#pragma unroll
      for (int t=0;t<4;++t) {
        float4 b = *(const float4*)&Bs[kk+t][tc*4];
#pragma unroll
        for (int rr=0;rr<4;++rr) {
          float av = a[rr][t];
          acc[rr][0] += av*b.x; acc[rr][1] += av*b.y;
          acc[rr][2] += av*b.z; acc[rr][3] += av*b.w;
        }
      }
    }
    __syncthreads();
  }
#pragma unroll
  for (int rr=0;rr<4;++rr) {
    float4 o; o.x=acc[rr][0]; o.y=acc[rr][1]; o.z=acc[rr][2]; o.w=acc[rr][3];
    *(float4*)&C[(size_t)(i0+tr*4+rr)*NN + j0 + tc*4] = o;
  }
}

// ---------- per-row max/min of K ----------
__global__ __launch_bounds__(256) void rowstat(const float* __restrict__ Km,
                                               float* __restrict__ rmax,
                                               float* __restrict__ rmin)
{
  __shared__ float s1[4], s2[4];
  int i = blockIdx.x;
  const float4* Kr = (const float4*)&Km[(size_t)i*NN];
  float mx=-3.4e38f, mn=3.4e38f;
  for (int f=threadIdx.x; f<NN/4; f+=256) {
    float4 k = Kr[f];
    mx = fmaxf(mx, fmaxf(fmaxf(k.x,k.y), fmaxf(k.z,k.w)));
    mn = fminf(mn, fminf(fminf(k.x,k.y), fminf(k.z,k.w)));
  }
  mx = waveMax(mx); mn = waveMin(mn);
  int lane = threadIdx.x & 63, wid = threadIdx.x >> 6;
  if (lane==0){ s1[wid]=mx; s2[wid]=mn; }
  __syncthreads();
  if (threadIdx.x==0) {
    rmax[i] = fmaxf(fmaxf(s1[0],s1[1]),fmaxf(s1[2],s1[3]));
    rmin[i] = fminf(fminf(s2[0],s2[1]),fminf(s2[2],s2[3]));
  }
}

__global__ __launch_bounds__(256) void greduce(const float* __restrict__ rmax,
                                               const float* __restrict__ rmin,
                                               float* __restrict__ stat)
{
  __shared__ float s1[4], s2[4];
  float mx=-3.4e38f, mn=3.4e38f;
  for (int i=threadIdx.x; i<NN; i+=256){ mx=fmaxf(mx,rmax[i]); mn=fminf(mn,rmin[i]); }
  mx = waveMax(mx); mn = waveMin(mn);
  int lane = threadIdx.x & 63, wid = threadIdx.x >> 6;
  if (lane==0){ s1[wid]=mx; s2[wid]=mn; }
  __syncthreads();
  if (threadIdx.x==0) {
    float gmx = fmaxf(fmaxf(s1[0],s1[1]),fmaxf(s1[2],s1[3]));
    float gmn = fminf(fminf(s2[0],s2[1]),fminf(s2[2],s2[3]));
    stat[0] = gmn;
    stat[1] = 1.f/(gmx-gmn);   // gamma = 1
  }
}

// ---------- K = exp((M0 - rowmax)*scale); optionally write M output ----------
__global__ __launch_bounds__(256) void transform_kernel(float* __restrict__ Km,
                                                        const float* __restrict__ rmax,
                                                        const float* __restrict__ stat,
                                                        float* __restrict__ Mout)
{
  const float gmin = stat[0], scale = stat[1];
  const int total4 = (NN*NN)/4;
  for (int f = blockIdx.x*256 + threadIdx.x; f < total4; f += gridDim.x*256) {
    int i = f >> 10;
    float rm = rmax[i];
    float4 m = ((const float4*)Km)[f];
    float4 k;
    k.x = __expf((m.x-rm)*scale);
    k.y = __expf((m.y-rm)*scale);
    k.z = __expf((m.z-rm)*scale);
    k.w = __expf((m.w-rm)*scale);
    ((float4*)Km)[f] = k;
    if (Mout) {
      size_t e = (size_t)f*4;
      Mout[e+0] = (m.x-gmin)*scale;
      Mout[e+1] = (m.y-gmin)*scale;
      Mout[e+2] = (m.z-gmin)*scale;
      Mout[e+3] = (m.w-gmin)*scale;
    }
  }
}

__global__ void vinit(float* __restrict__ v, double* __restrict__ acc)
{
  int g = blockIdx.x*256 + threadIdx.x;
  if (g < NN) v[g] = 1.f;
  if (g == 0) acc[0] = 0.0;
}

// ---------- y_i = sum_j K[i][j]*v[j]; out = recip ? r/y : y ----------
__global__ __launch_bounds__(256) void rowmv(const float* __restrict__ Km,
                                             const float* __restrict__ vin,
                                             float* __restrict__ outv,
                                             float rval, int recip)
{
  __shared__ float sred[4];
  int i = blockIdx.x;
  const float4* Kr = (const float4*)&Km[(size_t)i*NN];
  const float4* v4 = (const float4*)vin;
  float s = 0.f;
  for (int f = threadIdx.x; f < NN/4; f += 256) {
    float4 k = Kr[f], vv = v4[f];
    s += k.x*vv.x + k.y*vv.y + k.z*vv.z + k.w*vv.w;
  }
  s = waveSum(s);
  int lane = threadIdx.x & 63, wid = threadIdx.x >> 6;
  if (lane==0) sred[wid]=s;
  __syncthreads();
  if (threadIdx.x==0) {
    float tot = sred[0]+sred[1]+sred[2]+sred[3];
    outv[i] = recip ? rval/tot : tot;
  }
}

// ---------- column matvec partials: part[by][j] = sum_{i in chunk} K[i][j]*u[i] ----------
__global__ __launch_bounds__(256) void colpart(const float* __restrict__ Km,
                                               const float* __restrict__ u,
                                               float* __restrict__ part)
{
  __shared__ float su[128];
  int j = blockIdx.x*256 + threadIdx.x;
  int r0 = blockIdx.y*128;
  if (threadIdx.x < 128) su[threadIdx.x] = u[r0 + threadIdx.x];
  __syncthreads();
  float s = 0.f;
#pragma unroll 4
  for (int ii=0; ii<128; ++ii) s += Km[(size_t)(r0+ii)*NN + j] * su[ii];
  part[(size_t)blockIdx.y*NN + j] = s;
}

__global__ __launch_bounds__(256) void colfin(const float* __restrict__ part,
                                              float* __restrict__ v, float cval)
{
  int j = blockIdx.x*256 + threadIdx.x;
  float s = 0.f;
#pragma unroll
  for (int b=0;b<32;++b) s += part[(size_t)b*NN + j];
  v[j] = cval / s;
}

// ---------- final: P = K*v_j/y_i ; acc += sum (P - I)^2 ; optional P write ----------
__global__ __launch_bounds__(256) void losspass(const float* __restrict__ Km,
                                                const float* __restrict__ v,
                                                const float* __restrict__ y,
                                                double* __restrict__ acc,
                                                float* __restrict__ Pout)
{
  __shared__ float sred[4];
  const int total4 = (NN*NN)/4;
  float local = 0.f;
  for (int f = blockIdx.x*256 + threadIdx.x; f < total4; f += gridDim.x*256) {
    int i = f >> 10;
    int j0 = (f & 1023) << 2;
    float invy = 1.f / y[i];
    float4 k4 = ((const float4*)Km)[f];
    float4 v4 = ((const float4*)v)[f & 1023];
    float p0 = k4.x * v4.x * invy;
    float p1 = k4.y * v4.y * invy;
    float p2 = k4.z * v4.z * invy;
    float p3 = k4.w * v4.w * invy;
    if (Pout) {
      size_t e = (size_t)f*4;
      Pout[e+0]=p0; Pout[e+1]=p1; Pout[e+2]=p2; Pout[e+3]=p3;
    }
    float d0 = p0 - ((j0+0)==i ? 1.f : 0.f);
    float d1 = p1 - ((j0+1)==i ? 1.f : 0.f);
    float d2 = p2 - ((j0+2)==i ? 1.f : 0.f);
    float d3 = p3 - ((j0+3)==i ? 1.f : 0.f);
    local += d0*d0 + d1*d1 + d2*d2 + d3*d3;
  }
  float s = waveSum(local);
  int lane = threadIdx.x & 63, wid = threadIdx.x >> 6;
  if (lane==0) sred[wid]=s;
  __syncthreads();
  if (threadIdx.x==0) {
    double tot = (double)sred[0] + (double)sred[1] + (double)sred[2] + (double)sred[3];
    atomicAdd(acc, tot);
  }
}

__global__ void lossfin(const double* __restrict__ acc, float* __restrict__ outslot)
{
  if (threadIdx.x==0) *outslot = (float)sqrt(*acc);
}

__global__ void sumloss(float* __restrict__ out)
{
  if (threadIdx.x==0) out[0] = out[1]+out[2]+out[3]+out[4];
}

extern "C" void kernel_launch(void* const* d_in, const int* in_sizes, int n_in,
                              void* d_out, int out_size, void* d_ws, size_t ws_size,
                              hipStream_t stream)
{
  (void)in_sizes; (void)n_in; (void)out_size; (void)ws_size;
  const float* f_s  = (const float*)d_in[1];
  const float* l_s  = (const float*)d_in[2];
  const float* f_t  = (const float*)d_in[3];
  const float* l_t  = (const float*)d_in[4];
  const float* W_es = (const float*)d_in[5];
  const float* b_es = (const float*)d_in[6];
  const float* W_et = (const float*)d_in[7];
  const float* b_et = (const float*)d_in[8];
  const float* W_gs = (const float*)d_in[9];
  const float* b_gs = (const float*)d_in[10];
  const float* W_gt = (const float*)d_in[11];
  const float* b_gt = (const float*)d_in[12];
  float* out = (float*)d_out;

  double* accd = (double*)d_ws;
  float* base = (float*)d_ws + 4;
  float* f_es = base; base += NN*FF;
  float* f_et = base; base += NN*FF;
  float* f_gs = base; base += NN*FF;
  float* f_gt = base; base += NN*FF;
  float* S_s  = base; base += NN*CD;
  float* S_t  = base; base += NN*CD;
  float* w_s  = base; base += NN;
  float* w_t  = base; base += NN;
  int* idx_s  = (int*)base; base += NN*8;
  int* idx_t  = (int*)base; base += NN*8;
  float* rmax = base; base += NN;
  float* rmin = base; base += NN;
  float* stat = base; base += 16;
  float* u    = base; base += NN;
  float* v    = base; base += NN;
  float* y    = base; base += NN;
  float* colp = base; base += 32*NN;
  float* Kbuf = base; base += (size_t)NN*NN;

  float* Pout_final = out + 5;
  float* Mout_final = out + 5 + (size_t)NN*NN;

  const float R = 1.f/(float)NN;

  auto run_ot = [&](const float* ft, const float* fs, int slot, float* Pout, float* Mout){
    gemm_bt<<<dim3(64,64),256,0,stream>>>(ft, fs, Kbuf);
    rowstat<<<NN,256,0,stream>>>(Kbuf, rmax, rmin);
    greduce<<<1,256,0,stream>>>(rmax, rmin, stat);
    transform_kernel<<<4096,256,0,stream>>>(Kbuf, rmax, stat, Mout);
    vinit<<<16,256,0,stream>>>(v, accd);
    for (int it=0; it<OT_ITERS; ++it) {
      rowmv<<<NN,256,0,stream>>>(Kbuf, v, u, R, 1);
      colpart<<<dim3(16,32),256,0,stream>>>(Kbuf, u, colp);
      colfin<<<16,256,0,stream>>>(colp, v, R);
    }
    rowmv<<<NN,256,0,stream>>>(Kbuf, v, y, R, 0);
    losspass<<<4096,256,0,stream>>>(Kbuf, v, y, accd, Pout);
    lossfin<<<1,1,0,stream>>>(accd, out + slot);
  };

  // embeddings
  embed_gemm<<<256,256,0,stream>>>(f_s, W_es, b_es, f_es, 8192);
  embed_gemm<<<256,256,0,stream>>>(f_t, W_et, b_et, f_et, 8192);
  l2norm_rows<<<NN,128,0,stream>>>(f_es);
  l2norm_rows<<<NN,128,0,stream>>>(f_et);

  // loss_e = ot(f_et, f_es) -> slot 1
  run_ot(f_et, f_es, 1, nullptr, nullptr);

  // knn + encoders
  softmax_rows<<<NN,128,0,stream>>>(l_s, S_s, w_s);
  softmax_rows<<<NN,128,0,stream>>>(l_t, S_t, w_t);
  knn_topk<<<NN,256,0,stream>>>(S_s, w_s, idx_s);
  knn_topk<<<NN,256,0,stream>>>(S_t, w_t, idx_t);
  encoder_kernel<<<NN,128,0,stream>>>(f_es, idx_s, W_gs, b_gs, f_gs);
  encoder_kernel<<<NN,128,0,stream>>>(f_et, idx_t, W_gt, b_gt, f_gt);

  // loss_ge = ot(f_gt, f_es) -> slot 3
  run_ot(f_gt, f_es, 3, nullptr, nullptr);
  // loss_eg = ot(f_et, f_gt) -> slot 4
  run_ot(f_et, f_gt, 4, nullptr, nullptr);
  // loss_g = ot(f_gt, f_gs) -> slot 2, writes P and M
  run_ot(f_gt, f_gs, 2, Pout_final, Mout_final);

  sumloss<<<1,1,0,stream>>>(out);
}